// Round 3
// baseline (18.708 us; speedup 1.0000x reference)
//
#include <hip/hip_runtime.h>
#include <math.h>

#define EPS 1e-8f
#define D 128
#define K 5

// Fused kernel: 32 lanes per batch row (2 rows/wave), 8 rows per 256-thread
// block. Per-row pos-cosine + mean of K neg-cosines via float4 loads and a
// 5-step butterfly over the 32-lane group; block partial goes straight to
// out[0] via one fp32 global atomicAdd per block (hardware on gfx950).
// out[0] is zeroed by a 4-byte memsetAsync before launch; block 0 adds the
// constant 1.0 term. Final: out = 1 - mean(pos) + mean(neg).
__global__ __launch_bounds__(256) void simloss_fused(
    const float* __restrict__ ue,      // [B, D]
    const float* __restrict__ se,      // [B, D]
    const float* __restrict__ tu,      // [NU, D]
    const float* __restrict__ ts,      // [NS, D]
    const int*   __restrict__ busers,  // [B]
    const int*   __restrict__ negidx,  // [B, K]
    float* __restrict__ out,           // [1]
    int B, float invB)
{
    const int tid = blockIdx.x * 256 + threadIdx.x;
    const int row = tid >> 5;          // one row per 32 lanes
    const int r   = threadIdx.x & 31;  // lane within row

    float pos = 0.0f, neg = 0.0f;
    if (row < B) {
        const int uidx = busers[row];
        int nidx[K];
        #pragma unroll
        for (int k = 0; k < K; ++k) nidx[k] = negidx[row * K + k];

        const float4 a = ((const float4*)(ue + (size_t)row * D))[r];
        const float4 b = ((const float4*)(se + (size_t)row * D))[r];
        float dot = a.x*b.x + a.y*b.y + a.z*b.z + a.w*b.w;
        float na  = a.x*a.x + a.y*a.y + a.z*a.z + a.w*a.w;
        float nb  = b.x*b.x + b.y*b.y + b.z*b.z + b.w*b.w;

        const float4 c = ((const float4*)(tu + (size_t)uidx * D))[r];
        float nc = c.x*c.x + c.y*c.y + c.z*c.z + c.w*c.w;

        float dk[K], nk[K];
        #pragma unroll
        for (int k = 0; k < K; ++k) {
            const float4 e = ((const float4*)(ts + (size_t)nidx[k] * D))[r];
            dk[k] = c.x*e.x + c.y*e.y + c.z*e.z + c.w*e.w;
            nk[k] = e.x*e.x + e.y*e.y + e.z*e.z + e.w*e.w;
        }

        // Butterfly reduction within the 32-lane group (offsets < 32).
        #pragma unroll
        for (int off = 16; off > 0; off >>= 1) {
            dot += __shfl_xor(dot, off);
            na  += __shfl_xor(na,  off);
            nb  += __shfl_xor(nb,  off);
            nc  += __shfl_xor(nc,  off);
            #pragma unroll
            for (int k = 0; k < K; ++k) {
                dk[k] += __shfl_xor(dk[k], off);
                nk[k] += __shfl_xor(nk[k], off);
            }
        }

        // norms ~ sqrt(128) >> eps; rsqrtf error ~1e-6 << 2e-2 threshold
        pos = dot * rsqrtf(fmaxf(na, EPS * EPS)) * rsqrtf(fmaxf(nb, EPS * EPS));

        const float rc = rsqrtf(fmaxf(nc, EPS * EPS));
        float s = 0.0f;
        #pragma unroll
        for (int k = 0; k < K; ++k)
            s += dk[k] * rc * rsqrtf(fmaxf(nk[k], EPS * EPS));
        neg = s * (1.0f / K);
    }

    __shared__ float sp[8], sn[8];
    if (r == 0) { sp[threadIdx.x >> 5] = pos; sn[threadIdx.x >> 5] = neg; }
    __syncthreads();
    if (threadIdx.x == 0) {
        float tp = 0.0f, tn = 0.0f;
        #pragma unroll
        for (int i = 0; i < 8; ++i) { tp += sp[i]; tn += sn[i]; }
        float v = (tn - tp) * invB;
        if (blockIdx.x == 0) v += 1.0f;   // the "1 - mean(pos)" constant
        atomicAdd(out, v);                 // global fp32 atomic, device scope
    }
}

extern "C" void kernel_launch(void* const* d_in, const int* in_sizes, int n_in,
                              void* d_out, int out_size, void* d_ws, size_t ws_size,
                              hipStream_t stream) {
    const float* ue = (const float*)d_in[0];
    const float* se = (const float*)d_in[1];
    const float* tu = (const float*)d_in[2];
    const float* ts = (const float*)d_in[3];
    const int*   bu = (const int*)d_in[4];
    const int*   ni = (const int*)d_in[5];
    float* out = (float*)d_out;

    const int B = in_sizes[0] / D;               // 4096
    const int nblocks = (B * 32 + 255) / 256;    // 512 (8 rows per block)

    // out[0] must start at 0 every call (harness poisons once, never
    // re-poisons between graph replays).
    hipMemsetAsync(out, 0, sizeof(float), stream);
    simloss_fused<<<nblocks, 256, 0, stream>>>(ue, se, tu, ts, bu, ni, out,
                                               B, 1.0f / (float)B);
}